// Round 3
// baseline (372.683 us; speedup 1.0000x reference)
//
#include <hip/hip_runtime.h>
#include <math.h>

// FHN dynamics: row-wise max-abs normalization + sigmoid gating + 8 IMEX steps.
// One block (256 thr) per 2048-elem row; 8 elems/thread, register-resident.
// __launch_bounds__(256,8): cap VGPR<=64 -> 8 waves/SIMD (32/CU) to hide the
// load->rowmax-barrier->compute->store chain. State trimmed to 24 live floats:
// v[8], wd[8]=dt*w, Idt[8]=dt*I; step constants in SGPRs.
// Outputs stored nontemporal (never re-read; keep L2/L3 for the input stream).

#define ROWLEN 2048
#define BLOCK  256
#define EPT    8
#define F4PT   (EPT / 4)

// Native Clang vector type: __builtin_nontemporal_store requires it
// (HIP's float4 is a struct wrapper and is rejected).
typedef float nt4 __attribute__((ext_vector_type(4)));

__device__ __forceinline__ float clampf(float x, float lo, float hi) {
    return fminf(fmaxf(x, lo), hi);   // -> v_med3_f32
}

__global__ __launch_bounds__(BLOCK, 8)
void fhn_kernel(const float* __restrict__ stim,
                const float* __restrict__ a_p,
                const float* __restrict__ b_p,
                const float* __restrict__ dt_p,
                const int*   __restrict__ nsteps_p,
                float* __restrict__ out,      // [n_elem] response, then [n_elem] v
                int n_elem)
{
    const int row = blockIdx.x;
    const int tid = threadIdx.x;
    const nt4* __restrict__ srow4 = reinterpret_cast<const nt4*>(stim) + row * (ROWLEN / 4);

    // ---- coalesced float4 loads: lane t takes float4 slots {t, t+256} ----
    float s[EPT];
    #pragma unroll
    for (int i = 0; i < F4PT; ++i) {
        nt4 f = srow4[tid + i * BLOCK];
        s[4*i+0] = f.x; s[4*i+1] = f.y; s[4*i+2] = f.z; s[4*i+3] = f.w;
    }

    // ---- row max(|s|): local -> wave shuffle -> cross-wave via LDS ----
    float m = 0.0f;
    #pragma unroll
    for (int e = 0; e < EPT; ++e) m = fmaxf(m, fabsf(s[e]));
    #pragma unroll
    for (int off = 32; off > 0; off >>= 1)
        m = fmaxf(m, __shfl_down(m, off, 64));
    __shared__ float smax[BLOCK / 64];
    if ((tid & 63) == 0) smax[tid >> 6] = m;
    __syncthreads();
    m = fmaxf(fmaxf(smax[0], smax[1]), fmaxf(smax[2], smax[3]));

    const float scale     = fmaxf(m, 1e-6f);
    const float inv_scale = 1.0f / scale;

    // ---- uniform scalar params (land in SGPRs) ----
    const float a  = *a_p;
    const float b  = *b_p;
    const float dt = *dt_p;
    const int   n_steps = *nsteps_p;
    const float alpha     = dt * (1.0f / 12.5f);        // TAU = 12.5
    const float inv_denom = 1.0f / (1.0f + alpha * b);
    // Folded step constants (wd = dt*w formulation; clip(w,±3) -> clip(wd,±3dt)):
    const float c_v   = 1.0f + dt;          // vn = c_v*v - c_3*v^3 + (Idt - wd)
    const float c_3   = dt * (1.0f / 3.0f);
    const float A2    = dt * alpha;         // wd' = (wd + A2*vn + A3) * inv_denom
    const float A3    = dt * alpha * a;
    const float wclip = 3.0f * dt;

    // ---- conditioned input current, pre-scaled by dt: Idt = dt * I ----
    float Idt[EPT], v[EPT], wd[EPT];
    const float k = dt * inv_scale;
    #pragma unroll
    for (int e = 0; e < EPT; ++e) {
        const float as = fabsf(s[e]);
        // sigmoid((|s|-0.5)*10) via exp2: e2 = 2^((0.5-|s|)*10*log2e)
        const float e2   = __builtin_exp2f(fmaf(-14.4269504089f, as, 7.21347520444f));
        const float gate = __frcp_rn(1.0f + e2);
        Idt[e] = s[e] * k * fmaf(0.9f, gate, 0.1f);
        v[e]  = 0.0f;
        wd[e] = 0.0f;
    }

    // ---- IMEX FHN steps (w_next uses UNCLIPPED v_next, then both clip) ----
    for (int n = 0; n < n_steps; ++n) {
        #pragma unroll
        for (int e = 0; e < EPT; ++e) {
            const float ve  = v[e];
            const float vv  = ve * ve;
            const float q   = Idt[e] - wd[e];
            const float t1  = fmaf(c_v, ve, q);
            const float vn  = fmaf(-c_3, vv * ve, t1);          // raw v_next
            const float u   = wd[e] + A3;
            const float wdn = fmaf(A2, vn, u) * inv_denom;      // raw dt*w_next
            v[e]  = clampf(vn,  -3.0f,  3.0f);
            wd[e] = clampf(wdn, -wclip, wclip);
        }
    }

    // ---- epilogue: response = v * scale; also emit v (nontemporal stores) ----
    nt4* __restrict__ rrow4 = reinterpret_cast<nt4*>(out) + row * (ROWLEN / 4);
    nt4* __restrict__ vrow4 = reinterpret_cast<nt4*>(out + n_elem) + row * (ROWLEN / 4);
    #pragma unroll
    for (int i = 0; i < F4PT; ++i) {
        nt4 r, vv;
        r.x  = v[4*i+0] * scale; r.y  = v[4*i+1] * scale;
        r.z  = v[4*i+2] * scale; r.w  = v[4*i+3] * scale;
        vv.x = v[4*i+0];         vv.y = v[4*i+1];
        vv.z = v[4*i+2];         vv.w = v[4*i+3];
        __builtin_nontemporal_store(r,  rrow4 + tid + i * BLOCK);
        __builtin_nontemporal_store(vv, vrow4 + tid + i * BLOCK);
    }
}

extern "C" void kernel_launch(void* const* d_in, const int* in_sizes, int n_in,
                              void* d_out, int out_size, void* d_ws, size_t ws_size,
                              hipStream_t stream) {
    const float* stim = (const float*)d_in[0];
    const float* a_p  = (const float*)d_in[1];
    const float* b_p  = (const float*)d_in[2];
    const float* dt_p = (const float*)d_in[3];
    const int*   n_p  = (const int*)d_in[4];
    float* out = (float*)d_out;

    const int n_elem = in_sizes[0];
    const int rows = n_elem / ROWLEN;

    fhn_kernel<<<rows, BLOCK, 0, stream>>>(stim, a_p, b_p, dt_p, n_p, out, n_elem);
}